// Round 3
// baseline (70205.377 us; speedup 1.0000x reference)
//
#include <hip/hip_runtime.h>

#define BB 32
#define TT 150
#define LL 400
#define FEATD 512
#define RNND 512
#define ATTD 512
#define EMBD 256
#define VOCABD 5000
#define G3 1536
#define GRID 256
#define TPB 256
#define NCTR 8

__device__ __forceinline__ float fsigmoid(float x) { return 1.f / (1.f + __expf(-x)); }
__device__ __forceinline__ float ftanh(float x) {
    x = fminf(15.f, fmaxf(-15.f, x));
    float e = __expf(2.f * x);
    return 1.f - 2.f / (e + 1.f);
}
__device__ __forceinline__ void fma4(float4& a, const float4 w, const float s) {
    a.x += w.x * s; a.y += w.y * s; a.z += w.z * s; a.w += w.w * s;
}

// Grid barrier: 8 sharded device-scope counters, monotonic phase targets.
// All 256 blocks are co-resident (4 waves, ~40KB LDS each) so spinning is safe.
__device__ __forceinline__ void gridbar(unsigned* ctr, int ph) {
    __syncthreads();
    __threadfence();  // release: publish this phase's stores
    if (threadIdx.x == 0)
        atomicAdd(&ctr[blockIdx.x & (NCTR - 1)], 1u);
    if (threadIdx.x < NCTR) {
        unsigned tgt = (unsigned)ph * (GRID / NCTR);
        while (__hip_atomic_load(&ctr[threadIdx.x], __ATOMIC_RELAXED,
                                 __HIP_MEMORY_SCOPE_AGENT) < tgt)
            __builtin_amdgcn_s_sleep(2);
    }
    __threadfence();  // acquire: invalidate stale cached lines
    __syncthreads();
}

// ---------------- one-time feat_proj: [12800,512] @ [512,512] -> fp ----------------
__global__ void __launch_bounds__(TPB) k_feat_proj(const float* __restrict__ features,
                                                   const float* __restrict__ W1,
                                                   float* __restrict__ fp) {
    __shared__ float sa[64 * 68];
    int blt = blockIdx.x >> 2, at = blockIdx.x & 3;
    int bl0 = blt * 64;
    int tid = threadIdx.x;
    int aq = tid & 31, blg = tid >> 5;
    float4 acc[8] = {};
    for (int kc = 0; kc < FEATD; kc += 64) {
        __syncthreads();
        for (int it = 0; it < 16; ++it) {
            int lin = it * 256 + tid;
            int k = lin & 63, bl = lin >> 6;
            sa[k * 68 + bl] = features[((size_t)bl0 + bl) * FEATD + kc + k];
        }
        __syncthreads();
#pragma unroll 4
        for (int k = 0; k < 64; ++k) {
            float4 w = *(const float4*)&W1[(size_t)(kc + k) * ATTD + at * 128 + aq * 4];
            float4 s0 = *(const float4*)&sa[k * 68 + blg * 8];
            float4 s1 = *(const float4*)&sa[k * 68 + blg * 8 + 4];
            fma4(acc[0], w, s0.x); fma4(acc[1], w, s0.y);
            fma4(acc[2], w, s0.z); fma4(acc[3], w, s0.w);
            fma4(acc[4], w, s1.x); fma4(acc[5], w, s1.y);
            fma4(acc[6], w, s1.z); fma4(acc[7], w, s1.w);
        }
    }
#pragma unroll
    for (int i = 0; i < 8; ++i)
        *(float4*)&fp[((size_t)bl0 + blg * 8 + i) * ATTD + at * 128 + aq * 4] = acc[i];
}

// ---------------- persistent-kernel task bodies ----------------

// P1a: gate GEMM partials. 120 tasks: mx 24jt x 3ks, mh 24jt x 2ks. k-chunk 256.
__device__ void task_gates(int id, int t, const float* emb, const int* formula,
                           const float* Wk, const float* Wr, const float* h,
                           const float* outpp, float* mxp, float* mhp,
                           float* sm, int* stok) {
    int tid = threadIdx.x;
    bool isMX = id < 72;
    int jt, ks; const float* W; float* ob;
    if (isMX) { jt = id / 3; ks = id % 3; W = Wk; ob = mxp; }
    else { int r = id - 72; jt = r >> 1; ks = r & 1; W = Wr; ob = mhp; }
    int k0 = ks * 256;
    if (tid < BB) stok[tid] = formula[tid * TT + t];
    __syncthreads();
    // stage activations sm[k*36 + b], k in [0,256), b in [0,32)
    for (int it = 0; it < 32; ++it) {
        int lin = it * 256 + tid;
        int k = lin & 255, b = lin >> 8;
        float v;
        if (!isMX) v = h[(size_t)b * RNND + k0 + k];
        else if (ks == 0) v = emb[(size_t)stok[b] * EMBD + k];
        else {
            int kr = (ks - 1) * 256 + k;  // last_out = tanh(sum of out partials)
            v = ftanh(outpp[(size_t)(0 * BB + b) * RNND + kr] +
                      outpp[(size_t)(1 * BB + b) * RNND + kr] +
                      outpp[(size_t)(2 * BB + b) * RNND + kr] +
                      outpp[(size_t)(3 * BB + b) * RNND + kr]);
        }
        sm[k * 36 + b] = v;
    }
    __syncthreads();
    int jq = tid & 15, bg = tid >> 4;
    int j = jt * 64 + jq * 4;
    float4 a0 = {0, 0, 0, 0}, a1 = {0, 0, 0, 0};
#pragma unroll 4
    for (int k = 0; k < 256; ++k) {
        float4 w = *(const float4*)&W[(size_t)(k0 + k) * G3 + j];
        float2 s = *(const float2*)&sm[k * 36 + bg * 2];
        fma4(a0, w, s.x);
        fma4(a1, w, s.y);
    }
    int b = bg * 2;
    *(float4*)&ob[((size_t)ks * BB + b) * G3 + j] = a0;
    *(float4*)&ob[((size_t)ks * BB + b + 1) * G3 + j] = a1;
}

// P1b: materialize last_out (for logits next phase). 32 tasks (one per b).
__device__ void task_lo(int b, const float* outpp, float* lo) {
    int tid = threadIdx.x;
    for (int jj = tid; jj < RNND; jj += TPB) {
        float s = outpp[(size_t)(0 * BB + b) * RNND + jj] +
                  outpp[(size_t)(1 * BB + b) * RNND + jj] +
                  outpp[(size_t)(2 * BB + b) * RNND + jj] +
                  outpp[(size_t)(3 * BB + b) * RNND + jj];
        lo[(size_t)b * RNND + jj] = ftanh(s);
    }
}

// P2a: GRU combine -> h, then q partials (k-slice 256 x all 512 a).
// 16 tasks: ks(2) x bg(8, 4 b each).
__device__ void task_combine(int id, const float* mxp, const float* mhp,
                             const float* gruB, const float* W2,
                             float* h, float* qp, float* sm) {
    int tid = threadIdx.x;
    int ks = id >> 3, bg = id & 7;
    int b0 = bg * 4, k0 = ks * 256;
    int j = k0 + tid;
#pragma unroll
    for (int bi = 0; bi < 4; ++bi) {
        int b = b0 + bi;
        size_t m0 = (size_t)(0 * BB + b) * G3, m1 = (size_t)(1 * BB + b) * G3,
               m2 = (size_t)(2 * BB + b) * G3;
        float xz = gruB[j] + mxp[m0 + j] + mxp[m1 + j] + mxp[m2 + j];
        float xr = gruB[512 + j] + mxp[m0 + 512 + j] + mxp[m1 + 512 + j] + mxp[m2 + 512 + j];
        float xh = gruB[1024 + j] + mxp[m0 + 1024 + j] + mxp[m1 + 1024 + j] + mxp[m2 + 1024 + j];
        float rz = gruB[G3 + j] + mhp[m0 + j] + mhp[m1 + j];
        float rr = gruB[G3 + 512 + j] + mhp[m0 + 512 + j] + mhp[m1 + 512 + j];
        float rh = gruB[G3 + 1024 + j] + mhp[m0 + 1024 + j] + mhp[m1 + 1024 + j];
        float z = fsigmoid(xz + rz), r = fsigmoid(xr + rr);
        float hh = ftanh(xh + r * rh);
        float hn = z * h[(size_t)b * RNND + j] + (1.f - z) * hh;
        h[(size_t)b * RNND + j] = hn;
        sm[tid * 4 + bi] = hn;
    }
    __syncthreads();
    float ac0[4] = {0, 0, 0, 0}, ac1[4] = {0, 0, 0, 0};
#pragma unroll 4
    for (int k = 0; k < 256; ++k) {
        float4 s = *(const float4*)&sm[k * 4];
        float w0 = W2[(size_t)(k0 + k) * ATTD + tid];
        float w1 = W2[(size_t)(k0 + k) * ATTD + tid + 256];
        ac0[0] += s.x * w0; ac0[1] += s.y * w0; ac0[2] += s.z * w0; ac0[3] += s.w * w0;
        ac1[0] += s.x * w1; ac1[1] += s.y * w1; ac1[2] += s.z * w1; ac1[3] += s.w * w1;
    }
#pragma unroll
    for (int bi = 0; bi < 4; ++bi) {
        qp[((size_t)ks * BB + b0 + bi) * ATTD + tid] = ac0[bi];
        qp[((size_t)ks * BB + b0 + bi) * ATTD + tid + 256] = ac1[bi];
    }
}

// P2b: logits for step tt (one step behind). 160 tasks: vt(40 x 128v) x bg(4 x 8b).
__device__ void task_logits(int lid, int tt, const float* lo, const float* Wp,
                            float* out, float* sm) {
    int tid = threadIdx.x;
    int vt = lid >> 2, bg = lid & 3;
    int b0 = bg * 8;
    for (int it = 0; it < 16; ++it) {
        int lin = it * 256 + tid;
        int k = lin & 511, bi = lin >> 9;
        sm[k * 10 + bi] = lo[(size_t)(b0 + bi) * RNND + k];
    }
    __syncthreads();
    int vq = tid & 31, bh = tid >> 5;
    int v = vt * 128 + vq * 4;
    if (v < VOCABD) {
        int b = b0 + bh;
        float4 acc = {0, 0, 0, 0};
#pragma unroll 4
        for (int k = 0; k < 512; ++k) {
            float4 w = *(const float4*)&Wp[(size_t)k * VOCABD + v];
            fma4(acc, w, sm[k * 10 + bh]);
        }
        *(float4*)&out[((size_t)b * TT + tt) * VOCABD + v] = acc;
    }
}

// P3: q-reduce + scores + softmax-exp + ctx partials. 256 tasks: b(32) x ls(8 x 50 l).
__device__ void task_p3(int bid, const float* qp, const float* fp,
                        const float* V, const float* features,
                        float* ctxp, float* esump, float* sq, float* se) {
    int tid = threadIdx.x;
    int b = bid >> 3, ls = bid & 7, l0 = ls * 50;
    for (int a = tid; a < ATTD; a += TPB)
        sq[a] = qp[(size_t)(0 * BB + b) * ATTD + a] + qp[(size_t)(1 * BB + b) * ATTD + a];
    __syncthreads();
    int lane = tid & 63, wv = tid >> 6;
    float4 q0 = ((const float4*)sq)[lane], q1 = ((const float4*)sq)[64 + lane];
    float4 v0 = ((const float4*)V)[lane], v1 = ((const float4*)V)[64 + lane];
    for (int l = l0 + wv; l < l0 + 50; l += 4) {
        const float4* row = (const float4*)(fp + ((size_t)b * LL + l) * ATTD);
        float4 f0 = row[lane], f1 = row[64 + lane];
        float d = ftanh(f0.x + q0.x) * v0.x + ftanh(f0.y + q0.y) * v0.y +
                  ftanh(f0.z + q0.z) * v0.z + ftanh(f0.w + q0.w) * v0.w +
                  ftanh(f1.x + q1.x) * v1.x + ftanh(f1.y + q1.y) * v1.y +
                  ftanh(f1.z + q1.z) * v1.z + ftanh(f1.w + q1.w) * v1.w;
#pragma unroll
        for (int o = 32; o > 0; o >>= 1) d += __shfl_xor(d, o);
        if (lane == 0) se[l - l0] = __expf(d);  // |score| <= sum|V| ~ 20, fp32-safe
    }
    __syncthreads();
    if (tid < 64) {
        float x = (tid < 50) ? se[tid] : 0.f;
#pragma unroll
        for (int o = 32; o > 0; o >>= 1) x += __shfl_xor(x, o);
        if (tid == 0) esump[ls * BB + b] = x;
    }
    float c0 = 0.f, c1 = 0.f;
    for (int l = 0; l < 50; ++l) {
        float e = se[l];
        const float* fr = features + ((size_t)b * LL + l0 + l) * FEATD;
        c0 += e * fr[tid];
        c1 += e * fr[tid + 256];
    }
    ctxp[((size_t)ls * BB + b) * FEATD + tid] = c0;
    ctxp[((size_t)ls * BB + b) * FEATD + tid + 256] = c1;
}

// P4: out_state pre-act partials: cat(h, ctx/esum) @ outW. 64 tasks: jt(8) x ks(4) x bh(2).
__device__ void task_p4(int id, const float* h, const float* ctxp,
                        const float* esump, const float* outW,
                        float* outpp, float* sm, float* sinv) {
    int tid = threadIdx.x;
    int jt = id >> 3, ks = (id >> 1) & 3, bh = id & 1;
    int k0 = ks * 256, b0 = bh * 16;
    if (tid < 16) {
        int b = b0 + tid;
        float s = 0.f;
#pragma unroll
        for (int ls = 0; ls < 8; ++ls) s += esump[ls * BB + b];
        sinv[tid] = 1.f / s;
    }
    __syncthreads();
    for (int it = 0; it < 16; ++it) {
        int lin = it * 256 + tid;
        int k = lin & 255, bi = lin >> 8;
        int b = b0 + bi, kk = k0 + k;
        float v;
        if (kk < RNND) v = h[(size_t)b * RNND + kk];
        else {
            int f = kk - RNND;
            float c = 0.f;
#pragma unroll
            for (int ls = 0; ls < 8; ++ls) c += ctxp[((size_t)ls * BB + b) * FEATD + f];
            v = c * sinv[bi];
        }
        sm[k * 18 + bi] = v;
    }
    __syncthreads();
    int jq = tid & 15, bi = tid >> 4;
    int j = jt * 64 + jq * 4;
    float4 acc = {0, 0, 0, 0};
#pragma unroll 4
    for (int k = 0; k < 256; ++k) {
        float4 w = *(const float4*)&outW[(size_t)(k0 + k) * RNND + j];
        fma4(acc, w, sm[k * 18 + bi]);
    }
    *(float4*)&outpp[((size_t)ks * BB + b0 + bi) * RNND + j] = acc;
}

// ---------------- the persistent kernel ----------------
__global__ void __launch_bounds__(TPB) decoder_persist(
    const float* __restrict__ features, const float* __restrict__ emb,
    const float* __restrict__ Wk, const float* __restrict__ Wr,
    const float* __restrict__ gruB, const float* __restrict__ W2,
    const float* __restrict__ V, const float* __restrict__ outW,
    const float* __restrict__ Wp, const int* __restrict__ formula,
    const float* __restrict__ fp,
    float* mxp, float* mhp, float* qp, float* ctxp, float* esump,
    float* outpp, float* h, float* lo, float* out, unsigned* ctr) {
    __shared__ float sm[9216];   // 36.9KB: gates sk[256][36] / logits sot[512][10] / p4 sk[256][18]
    __shared__ float sq[512];
    __shared__ float se[64];
    __shared__ float sinv[16];
    __shared__ int stok[32];
    int bid = blockIdx.x;
    int ph = 0;
    for (int t = 0; t < TT; ++t) {
        // P1: gate GEMM partials (t) || materialize last_out(t-1)
        if (bid < 120) task_gates(bid, t, emb, formula, Wk, Wr, h, outpp, mxp, mhp, sm, stok);
        else if (bid < 152) task_lo(bid - 120, outpp, lo);
        gridbar(ctr, ++ph);
        // P2: combine -> h(t), q partials || logits(t-1)
        if (bid < 16) task_combine(bid, mxp, mhp, gruB, W2, h, qp, sm);
        else if (bid < 176 && t > 0) task_logits(bid - 16, t - 1, lo, Wp, out, sm);
        gridbar(ctr, ++ph);
        // P3: scores + softmax-exp + ctx partials
        task_p3(bid, qp, fp, V, features, ctxp, esump, sq, se);
        gridbar(ctr, ++ph);
        // P4: out_state pre-activation partials
        if (bid < 64) task_p4(bid, h, ctxp, esump, outW, outpp, sm, sinv);
        gridbar(ctr, ++ph);
    }
    // tail: logits for t = 149
    if (bid < 32) task_lo(bid, outpp, lo);
    gridbar(ctr, ++ph);
    if (bid < 160) task_logits(bid, TT - 1, lo, Wp, out, sm);
}

extern "C" void kernel_launch(void* const* d_in, const int* in_sizes, int n_in,
                              void* d_out, int out_size, void* d_ws, size_t ws_size,
                              hipStream_t stream) {
    const float* features  = (const float*)d_in[0];
    const float* initstate = (const float*)d_in[1];
    const float* emb       = (const float*)d_in[2];
    const float* gruK      = (const float*)d_in[3];
    const float* gruR      = (const float*)d_in[4];
    const float* gruB      = (const float*)d_in[5];
    const float* W1        = (const float*)d_in[6];
    const float* W2        = (const float*)d_in[7];
    const float* V         = (const float*)d_in[8];
    const float* outW      = (const float*)d_in[9];
    const float* projW     = (const float*)d_in[10];
    const int*   formula   = (const int*)d_in[11];
    float* logits = (float*)d_out;

    float* ws = (float*)d_ws;
    unsigned* ctr = (unsigned*)ws;                    // 32 floats reserved
    float* h     = ws + 32;                           // 16384
    float* lo    = h + (size_t)BB * RNND;             // 16384
    float* mxp   = lo + (size_t)BB * RNND;            // 3*32*1536
    float* mhp   = mxp + (size_t)3 * BB * G3;         // 2*32*1536
    float* qp    = mhp + (size_t)2 * BB * G3;         // 2*32*512
    float* ctxp  = qp + (size_t)2 * BB * ATTD;        // 8*32*512
    float* esump = ctxp + (size_t)8 * BB * FEATD;     // 256
    float* outpp = esump + 8 * BB;                    // 4*32*512
    float* fp    = outpp + (size_t)4 * BB * RNND;     // 6,553,600

    hipMemsetAsync(ctr, 0, 128, stream);
    hipMemsetAsync(outpp, 0, (size_t)4 * BB * RNND * sizeof(float), stream);
    hipMemcpyAsync(h, initstate, (size_t)BB * RNND * sizeof(float),
                   hipMemcpyDeviceToDevice, stream);

    k_feat_proj<<<800, TPB, 0, stream>>>(features, W1, fp);

    decoder_persist<<<GRID, TPB, 0, stream>>>(
        features, emb, gruK, gruR, gruB, W2, V, outW, projW, formula, fp,
        mxp, mhp, qp, ctxp, esump, outpp, h, lo, logits, ctr);
}

// Round 4
// 56544.501 us; speedup vs baseline: 1.2416x; 1.2416x over previous
//
#include <hip/hip_runtime.h>

#define BB 32
#define TT 150
#define LL 400
#define FEATD 512
#define RNND 512
#define ATTD 512
#define EMBD 256
#define VOCABD 5000
#define G3 1536
#define GRID 256
#define TPB 256
#define NCTR 8

__device__ __forceinline__ float fsigmoid(float x) { return 1.f / (1.f + __expf(-x)); }
__device__ __forceinline__ float ftanh(float x) {
    x = fminf(15.f, fmaxf(-15.f, x));
    float e = __expf(2.f * x);
    return 1.f - 2.f / (e + 1.f);
}
__device__ __forceinline__ void fma4(float4& a, const float4 w, const float s) {
    a.x += w.x * s; a.y += w.y * s; a.z += w.z * s; a.w += w.w * s;
}

// Cross-block (cross-XCD) coherent accesses: agent-scope relaxed atomics.
// These bypass the non-coherent per-XCD L2 and hit the shared coherent point,
// so we never need cache-invalidating fences (which killed round 3: every
// gridbar's __threadfence invalidated L2 -> 55MB/step refetched from HBM).
__device__ __forceinline__ float gld(const float* p) {
    return __hip_atomic_load(p, __ATOMIC_RELAXED, __HIP_MEMORY_SCOPE_AGENT);
}
__device__ __forceinline__ void gst(float* p, float v) {
    __hip_atomic_store(p, v, __ATOMIC_RELAXED, __HIP_MEMORY_SCOPE_AGENT);
}

// Grid barrier with NO cache fences. All cross-block data moves via gld/gst
// (already coherent); s_waitcnt vmcnt(0) ensures this wave's stores reached
// the coherence point before we signal arrival.
__device__ __forceinline__ void gridbar(unsigned* ctr, int ph) {
    asm volatile("s_waitcnt vmcnt(0)" ::: "memory");
    __syncthreads();
    if (threadIdx.x == 0)
        __hip_atomic_fetch_add(&ctr[blockIdx.x & (NCTR - 1)], 1u,
                               __ATOMIC_RELAXED, __HIP_MEMORY_SCOPE_AGENT);
    if (threadIdx.x < NCTR) {
        unsigned tgt = (unsigned)ph * (GRID / NCTR);
        while (__hip_atomic_load(&ctr[threadIdx.x], __ATOMIC_RELAXED,
                                 __HIP_MEMORY_SCOPE_AGENT) < tgt)
            __builtin_amdgcn_s_sleep(4);
    }
    __syncthreads();
}

// ---------------- one-time feat_proj: [12800,512] @ [512,512] -> fp ----------------
__global__ void __launch_bounds__(TPB) k_feat_proj(const float* __restrict__ features,
                                                   const float* __restrict__ W1,
                                                   float* __restrict__ fp) {
    __shared__ float sa[64 * 68];
    int blt = blockIdx.x >> 2, at = blockIdx.x & 3;
    int bl0 = blt * 64;
    int tid = threadIdx.x;
    int aq = tid & 31, blg = tid >> 5;
    float4 acc[8] = {};
    for (int kc = 0; kc < FEATD; kc += 64) {
        __syncthreads();
        for (int it = 0; it < 16; ++it) {
            int lin = it * 256 + tid;
            int k = lin & 63, bl = lin >> 6;
            sa[k * 68 + bl] = features[((size_t)bl0 + bl) * FEATD + kc + k];
        }
        __syncthreads();
#pragma unroll 4
        for (int k = 0; k < 64; ++k) {
            float4 w = *(const float4*)&W1[(size_t)(kc + k) * ATTD + at * 128 + aq * 4];
            float4 s0 = *(const float4*)&sa[k * 68 + blg * 8];
            float4 s1 = *(const float4*)&sa[k * 68 + blg * 8 + 4];
            fma4(acc[0], w, s0.x); fma4(acc[1], w, s0.y);
            fma4(acc[2], w, s0.z); fma4(acc[3], w, s0.w);
            fma4(acc[4], w, s1.x); fma4(acc[5], w, s1.y);
            fma4(acc[6], w, s1.z); fma4(acc[7], w, s1.w);
        }
    }
#pragma unroll
    for (int i = 0; i < 8; ++i)
        *(float4*)&fp[((size_t)bl0 + blg * 8 + i) * ATTD + at * 128 + aq * 4] = acc[i];
}

// ---------------- persistent-kernel task bodies ----------------

// P1a: gate GEMM partials. 120 tasks: mx 24jt x 3ks, mh 24jt x 2ks. k-chunk 256.
__device__ void task_gates(int id, int t, const float* emb, const int* formula,
                           const float* Wk, const float* Wr, const float* h,
                           const float* outpp, float* mxp, float* mhp,
                           float* sm, int* stok) {
    int tid = threadIdx.x;
    bool isMX = id < 72;
    int jt, ks; const float* W; float* ob;
    if (isMX) { jt = id / 3; ks = id % 3; W = Wk; ob = mxp; }
    else { int r = id - 72; jt = r >> 1; ks = r & 1; W = Wr; ob = mhp; }
    int k0 = ks * 256;
    if (tid < BB) stok[tid] = formula[tid * TT + t];
    __syncthreads();
    // stage activations sm[k*36 + b]
    for (int it = 0; it < 32; ++it) {
        int lin = it * 256 + tid;
        int k = lin & 255, b = lin >> 8;
        float v;
        if (!isMX) v = gld(&h[(size_t)b * RNND + k0 + k]);
        else if (ks == 0) v = emb[(size_t)stok[b] * EMBD + k];
        else {
            int kr = (ks - 1) * 256 + k;  // last_out = tanh(sum of out partials)
            v = ftanh(gld(&outpp[(size_t)(0 * BB + b) * RNND + kr]) +
                      gld(&outpp[(size_t)(1 * BB + b) * RNND + kr]) +
                      gld(&outpp[(size_t)(2 * BB + b) * RNND + kr]) +
                      gld(&outpp[(size_t)(3 * BB + b) * RNND + kr]));
        }
        sm[k * 36 + b] = v;
    }
    __syncthreads();
    int jq = tid & 15, bg = tid >> 4;
    int j = jt * 64 + jq * 4;
    float4 a0 = {0, 0, 0, 0}, a1 = {0, 0, 0, 0};
#pragma unroll 4
    for (int k = 0; k < 256; ++k) {
        float4 w = *(const float4*)&W[(size_t)(k0 + k) * G3 + j];
        float2 s = *(const float2*)&sm[k * 36 + bg * 2];
        fma4(a0, w, s.x);
        fma4(a1, w, s.y);
    }
    int b = bg * 2;
    size_t o0 = ((size_t)ks * BB + b) * G3 + j;
    size_t o1 = ((size_t)ks * BB + b + 1) * G3 + j;
    gst(&ob[o0], a0.x); gst(&ob[o0 + 1], a0.y); gst(&ob[o0 + 2], a0.z); gst(&ob[o0 + 3], a0.w);
    gst(&ob[o1], a1.x); gst(&ob[o1 + 1], a1.y); gst(&ob[o1 + 2], a1.z); gst(&ob[o1 + 3], a1.w);
}

// P1b: materialize last_out (for logits next phase). 32 tasks (one per b).
__device__ void task_lo(int b, const float* outpp, float* lo) {
    int tid = threadIdx.x;
    for (int jj = tid; jj < RNND; jj += TPB) {
        float s = gld(&outpp[(size_t)(0 * BB + b) * RNND + jj]) +
                  gld(&outpp[(size_t)(1 * BB + b) * RNND + jj]) +
                  gld(&outpp[(size_t)(2 * BB + b) * RNND + jj]) +
                  gld(&outpp[(size_t)(3 * BB + b) * RNND + jj]);
        gst(&lo[(size_t)b * RNND + jj], ftanh(s));
    }
}

// P2a: GRU combine -> h, then q partials. 16 tasks: ks(2) x bg(8, 4 b each).
__device__ void task_combine(int id, const float* mxp, const float* mhp,
                             const float* gruB, const float* W2,
                             float* h, float* qp, float* sm) {
    int tid = threadIdx.x;
    int ks = id >> 3, bg = id & 7;
    int b0 = bg * 4, k0 = ks * 256;
    int j = k0 + tid;
#pragma unroll
    for (int bi = 0; bi < 4; ++bi) {
        int b = b0 + bi;
        size_t m0 = (size_t)(0 * BB + b) * G3, m1 = (size_t)(1 * BB + b) * G3,
               m2 = (size_t)(2 * BB + b) * G3;
        float xz = gruB[j] + gld(&mxp[m0 + j]) + gld(&mxp[m1 + j]) + gld(&mxp[m2 + j]);
        float xr = gruB[512 + j] + gld(&mxp[m0 + 512 + j]) + gld(&mxp[m1 + 512 + j]) + gld(&mxp[m2 + 512 + j]);
        float xh = gruB[1024 + j] + gld(&mxp[m0 + 1024 + j]) + gld(&mxp[m1 + 1024 + j]) + gld(&mxp[m2 + 1024 + j]);
        float rz = gruB[G3 + j] + gld(&mhp[m0 + j]) + gld(&mhp[m1 + j]);
        float rr = gruB[G3 + 512 + j] + gld(&mhp[m0 + 512 + j]) + gld(&mhp[m1 + 512 + j]);
        float rh = gruB[G3 + 1024 + j] + gld(&mhp[m0 + 1024 + j]) + gld(&mhp[m1 + 1024 + j]);
        float z = fsigmoid(xz + rz), r = fsigmoid(xr + rr);
        float hh = ftanh(xh + r * rh);
        float hn = z * gld(&h[(size_t)b * RNND + j]) + (1.f - z) * hh;
        gst(&h[(size_t)b * RNND + j], hn);
        sm[tid * 4 + bi] = hn;
    }
    __syncthreads();
    float ac0[4] = {0, 0, 0, 0}, ac1[4] = {0, 0, 0, 0};
#pragma unroll 4
    for (int k = 0; k < 256; ++k) {
        float4 s = *(const float4*)&sm[k * 4];
        float w0 = W2[(size_t)(k0 + k) * ATTD + tid];
        float w1 = W2[(size_t)(k0 + k) * ATTD + tid + 256];
        ac0[0] += s.x * w0; ac0[1] += s.y * w0; ac0[2] += s.z * w0; ac0[3] += s.w * w0;
        ac1[0] += s.x * w1; ac1[1] += s.y * w1; ac1[2] += s.z * w1; ac1[3] += s.w * w1;
    }
#pragma unroll
    for (int bi = 0; bi < 4; ++bi) {
        gst(&qp[((size_t)ks * BB + b0 + bi) * ATTD + tid], ac0[bi]);
        gst(&qp[((size_t)ks * BB + b0 + bi) * ATTD + tid + 256], ac1[bi]);
    }
}

// P2b: logits for step tt (one step behind). 160 tasks: vt(40 x 128v) x bg(4 x 8b).
__device__ void task_logits(int lid, int tt, const float* lo, const float* Wp,
                            float* out, float* sm) {
    int tid = threadIdx.x;
    int vt = lid >> 2, bg = lid & 3;
    int b0 = bg * 8;
    for (int it = 0; it < 16; ++it) {
        int lin = it * 256 + tid;
        int k = lin & 511, bi = lin >> 9;
        sm[k * 10 + bi] = gld(&lo[(size_t)(b0 + bi) * RNND + k]);
    }
    __syncthreads();
    int vq = tid & 31, bh = tid >> 5;
    int v = vt * 128 + vq * 4;
    if (v < VOCABD) {
        int b = b0 + bh;
        float4 acc = {0, 0, 0, 0};
#pragma unroll 4
        for (int k = 0; k < 512; ++k) {
            float4 w = *(const float4*)&Wp[(size_t)k * VOCABD + v];
            fma4(acc, w, sm[k * 10 + bh]);
        }
        *(float4*)&out[((size_t)b * TT + tt) * VOCABD + v] = acc;  // host-only reader
    }
}

// P3: q-reduce + scores + softmax-exp + ctx partials. 256 tasks: b(32) x ls(8 x 50 l).
__device__ void task_p3(int bid, const float* qp, const float* fp,
                        const float* V, const float* features,
                        float* ctxp, float* esump, float* sq, float* se) {
    int tid = threadIdx.x;
    int b = bid >> 3, ls = bid & 7, l0 = ls * 50;
    for (int a = tid; a < ATTD; a += TPB)
        sq[a] = gld(&qp[(size_t)(0 * BB + b) * ATTD + a]) +
                gld(&qp[(size_t)(1 * BB + b) * ATTD + a]);
    __syncthreads();
    int lane = tid & 63, wv = tid >> 6;
    float4 q0 = ((const float4*)sq)[lane], q1 = ((const float4*)sq)[64 + lane];
    float4 v0 = ((const float4*)V)[lane], v1 = ((const float4*)V)[64 + lane];
    for (int l = l0 + wv; l < l0 + 50; l += 4) {
        const float4* row = (const float4*)(fp + ((size_t)b * LL + l) * ATTD);
        float4 f0 = row[lane], f1 = row[64 + lane];
        float d = ftanh(f0.x + q0.x) * v0.x + ftanh(f0.y + q0.y) * v0.y +
                  ftanh(f0.z + q0.z) * v0.z + ftanh(f0.w + q0.w) * v0.w +
                  ftanh(f1.x + q1.x) * v1.x + ftanh(f1.y + q1.y) * v1.y +
                  ftanh(f1.z + q1.z) * v1.z + ftanh(f1.w + q1.w) * v1.w;
#pragma unroll
        for (int o = 32; o > 0; o >>= 1) d += __shfl_xor(d, o);
        if (lane == 0) se[l - l0] = __expf(d);  // |score| <= sum|V| ~ 20, fp32-safe
    }
    __syncthreads();
    if (tid < 64) {
        float x = (tid < 50) ? se[tid] : 0.f;
#pragma unroll
        for (int o = 32; o > 0; o >>= 1) x += __shfl_xor(x, o);
        if (tid == 0) gst(&esump[ls * BB + b], x);
    }
    float c0 = 0.f, c1 = 0.f;
    for (int l = 0; l < 50; ++l) {
        float e = se[l];
        const float* fr = features + ((size_t)b * LL + l0 + l) * FEATD;
        c0 += e * fr[tid];
        c1 += e * fr[tid + 256];
    }
    gst(&ctxp[((size_t)ls * BB + b) * FEATD + tid], c0);
    gst(&ctxp[((size_t)ls * BB + b) * FEATD + tid + 256], c1);
}

// P4: out_state pre-act partials: cat(h, ctx/esum) @ outW. 64 tasks: jt(8) x ks(4) x bh(2).
__device__ void task_p4(int id, const float* h, const float* ctxp,
                        const float* esump, const float* outW,
                        float* outpp, float* sm, float* sinv) {
    int tid = threadIdx.x;
    int jt = id >> 3, ks = (id >> 1) & 3, bh = id & 1;
    int k0 = ks * 256, b0 = bh * 16;
    if (tid < 16) {
        int b = b0 + tid;
        float s = 0.f;
#pragma unroll
        for (int ls = 0; ls < 8; ++ls) s += gld(&esump[ls * BB + b]);
        sinv[tid] = 1.f / s;
    }
    __syncthreads();
    for (int it = 0; it < 16; ++it) {
        int lin = it * 256 + tid;
        int k = lin & 255, bi = lin >> 8;
        int b = b0 + bi, kk = k0 + k;
        float v;
        if (kk < RNND) v = gld(&h[(size_t)b * RNND + kk]);
        else {
            int f = kk - RNND;
            float c = 0.f;
#pragma unroll
            for (int ls = 0; ls < 8; ++ls) c += gld(&ctxp[((size_t)ls * BB + b) * FEATD + f]);
            v = c * sinv[bi];
        }
        sm[k * 18 + bi] = v;
    }
    __syncthreads();
    int jq = tid & 15, bi = tid >> 4;
    int j = jt * 64 + jq * 4;
    float4 acc = {0, 0, 0, 0};
#pragma unroll 4
    for (int k = 0; k < 256; ++k) {
        float4 w = *(const float4*)&outW[(size_t)(k0 + k) * RNND + j];
        fma4(acc, w, sm[k * 18 + bi]);
    }
    size_t o = ((size_t)ks * BB + b0 + bi) * RNND + j;
    gst(&outpp[o], acc.x); gst(&outpp[o + 1], acc.y);
    gst(&outpp[o + 2], acc.z); gst(&outpp[o + 3], acc.w);
}

// ---------------- the persistent kernel ----------------
__global__ void __launch_bounds__(TPB) decoder_persist(
    const float* __restrict__ features, const float* __restrict__ emb,
    const float* __restrict__ Wk, const float* __restrict__ Wr,
    const float* __restrict__ gruB, const float* __restrict__ W2,
    const float* __restrict__ V, const float* __restrict__ outW,
    const float* __restrict__ Wp, const int* __restrict__ formula,
    const float* __restrict__ fp,
    float* mxp, float* mhp, float* qp, float* ctxp, float* esump,
    float* outpp, float* h, float* lo, float* out, unsigned* ctr) {
    __shared__ float sm[9216];   // gates sk[256][36] / logits [512][10] / p4 [256][18]
    __shared__ float sq[512];
    __shared__ float se[64];
    __shared__ float sinv[16];
    __shared__ int stok[32];
    int bid = blockIdx.x;
    int ph = 0;
    for (int t = 0; t < TT; ++t) {
        // P1: gate GEMM partials (t) || materialize last_out(t-1)
        if (bid < 120) task_gates(bid, t, emb, formula, Wk, Wr, h, outpp, mxp, mhp, sm, stok);
        else if (bid < 152) task_lo(bid - 120, outpp, lo);
        gridbar(ctr, ++ph);
        // P2: combine -> h(t), q partials || logits(t-1)
        if (bid < 16) task_combine(bid, mxp, mhp, gruB, W2, h, qp, sm);
        else if (bid < 176 && t > 0) task_logits(bid - 16, t - 1, lo, Wp, out, sm);
        gridbar(ctr, ++ph);
        // P3: scores + softmax-exp + ctx partials
        task_p3(bid, qp, fp, V, features, ctxp, esump, sq, se);
        gridbar(ctr, ++ph);
        // P4: out_state pre-activation partials
        if (bid < 64) task_p4(bid, h, ctxp, esump, outW, outpp, sm, sinv);
        gridbar(ctr, ++ph);
    }
    // tail: logits for t = 149
    if (bid < 32) task_lo(bid, outpp, lo);
    gridbar(ctr, ++ph);
    if (bid < 160) task_logits(bid, TT - 1, lo, Wp, out, sm);
}

extern "C" void kernel_launch(void* const* d_in, const int* in_sizes, int n_in,
                              void* d_out, int out_size, void* d_ws, size_t ws_size,
                              hipStream_t stream) {
    const float* features  = (const float*)d_in[0];
    const float* initstate = (const float*)d_in[1];
    const float* emb       = (const float*)d_in[2];
    const float* gruK      = (const float*)d_in[3];
    const float* gruR      = (const float*)d_in[4];
    const float* gruB      = (const float*)d_in[5];
    const float* W1        = (const float*)d_in[6];
    const float* W2        = (const float*)d_in[7];
    const float* V         = (const float*)d_in[8];
    const float* outW      = (const float*)d_in[9];
    const float* projW     = (const float*)d_in[10];
    const int*   formula   = (const int*)d_in[11];
    float* logits = (float*)d_out;

    float* ws = (float*)d_ws;
    unsigned* ctr = (unsigned*)ws;                    // 32 floats reserved
    float* h     = ws + 32;                           // 16384
    float* lo    = h + (size_t)BB * RNND;             // 16384
    float* mxp   = lo + (size_t)BB * RNND;            // 3*32*1536
    float* mhp   = mxp + (size_t)3 * BB * G3;         // 2*32*1536
    float* qp    = mhp + (size_t)2 * BB * G3;         // 2*32*512
    float* ctxp  = qp + (size_t)2 * BB * ATTD;        // 8*32*512
    float* esump = ctxp + (size_t)8 * BB * FEATD;     // 256
    float* outpp = esump + 8 * BB;                    // 4*32*512
    float* fp    = outpp + (size_t)4 * BB * RNND;     // 6,553,600

    hipMemsetAsync(ctr, 0, 128, stream);
    hipMemsetAsync(outpp, 0, (size_t)4 * BB * RNND * sizeof(float), stream);
    hipMemcpyAsync(h, initstate, (size_t)BB * RNND * sizeof(float),
                   hipMemcpyDeviceToDevice, stream);

    k_feat_proj<<<800, TPB, 0, stream>>>(features, W1, fp);

    decoder_persist<<<GRID, TPB, 0, stream>>>(
        features, emb, gruK, gruR, gruB, W2, V, outW, projW, formula, fp,
        mxp, mhp, qp, ctxp, esump, outpp, h, lo, logits, ctr);
}

// Round 5
// 19002.768 us; speedup vs baseline: 3.6945x; 2.9756x over previous
//
#include <hip/hip_runtime.h>

#define BB 32
#define TT 150
#define LL 400
#define FEATD 512
#define RNND 512
#define ATTD 512
#define EMBD 256
#define VOCABD 5000
#define G3 1536

__device__ __forceinline__ float fsigmoid(float x) { return 1.f / (1.f + __expf(-x)); }
__device__ __forceinline__ float ftanh(float x) {
    x = fminf(15.f, fmaxf(-15.f, x));
    float e = __expf(2.f * x);
    return 1.f - 2.f / (e + 1.f);
}
__device__ __forceinline__ void fma4(float4& a, const float4 w, const float s) {
    a.x += w.x * s; a.y += w.y * s; a.z += w.z * s; a.w += w.w * s;
}

// ---------------- one-time feat_proj: [B*L,512] @ [512,512] -> fp ----------------
__global__ void __launch_bounds__(256) k_feat_proj(const float* __restrict__ features,
                                                   const float* __restrict__ W1,
                                                   float* __restrict__ fp) {
    __shared__ float sa[64 * 68];
    int blt = blockIdx.x >> 2, at = blockIdx.x & 3;
    int bl0 = blt * 64;
    int tid = threadIdx.x;
    int aq = tid & 31, blg = tid >> 5;
    float4 acc[8] = {};
    for (int kc = 0; kc < FEATD; kc += 64) {
        __syncthreads();
        for (int it = 0; it < 16; ++it) {
            int lin = it * 256 + tid;
            int k = lin & 63, bl = lin >> 6;
            sa[k * 68 + bl] = features[((size_t)bl0 + bl) * FEATD + kc + k];
        }
        __syncthreads();
#pragma unroll 4
        for (int k = 0; k < 64; ++k) {
            float4 w = *(const float4*)&W1[(size_t)(kc + k) * ATTD + at * 128 + aq * 4];
            float4 s0 = *(const float4*)&sa[k * 68 + blg * 8];
            float4 s1 = *(const float4*)&sa[k * 68 + blg * 8 + 4];
            fma4(acc[0], w, s0.x); fma4(acc[1], w, s0.y);
            fma4(acc[2], w, s0.z); fma4(acc[3], w, s0.w);
            fma4(acc[4], w, s1.x); fma4(acc[5], w, s1.y);
            fma4(acc[6], w, s1.z); fma4(acc[7], w, s1.w);
        }
    }
#pragma unroll
    for (int i = 0; i < 8; ++i)
        *(float4*)&fp[((size_t)bl0 + blg * 8 + i) * ATTD + at * 128 + aq * 4] = acc[i];
}

// ---------------- K1: gate GEMM partials. 120 blocks x 256 threads ----------------
// mx: [emb(tok) | lo(t-1)] (K=768) @ Wk -> mxp[3 ks], mh: h @ Wr -> mhp[2 ks].
// los slot t holds lo(t-1); slot 0 is zeros.
__global__ void __launch_bounds__(256) k_gates(
    const float* __restrict__ emb, const int* __restrict__ formula,
    const float* __restrict__ Wk, const float* __restrict__ Wr,
    const float* __restrict__ h, const float* __restrict__ los,
    float* __restrict__ mxp, float* __restrict__ mhp, int t) {
    __shared__ float sm[256 * 36];
    __shared__ int stok[BB];
    int id = blockIdx.x, tid = threadIdx.x;
    bool isMX = id < 72;
    int jt, ks; const float* W; float* ob;
    if (isMX) { jt = id / 3; ks = id % 3; W = Wk; ob = mxp; }
    else { int r = id - 72; jt = r >> 1; ks = r & 1; W = Wr; ob = mhp; }
    int k0 = ks * 256;
    const float* lo = los + (size_t)t * BB * RNND;
    if (isMX && ks == 0 && tid < BB) stok[tid] = formula[tid * TT + t];
    __syncthreads();
    // stage activations sm[k*36+b]
    for (int it = 0; it < 32; ++it) {
        int lin = it * 256 + tid;
        int k = lin & 255, b = lin >> 8;
        float v;
        if (!isMX) v = h[(size_t)b * RNND + k0 + k];
        else if (ks == 0) v = emb[(size_t)stok[b] * EMBD + k];
        else v = lo[(size_t)b * RNND + (ks - 1) * 256 + k];
        sm[k * 36 + b] = v;
    }
    __syncthreads();
    int jq = tid & 15, bg = tid >> 4;
    int j = jt * 64 + jq * 4;
    float4 a0 = {0, 0, 0, 0}, a1 = {0, 0, 0, 0};
#pragma unroll 4
    for (int k = 0; k < 256; ++k) {
        float4 w = *(const float4*)&W[(size_t)(k0 + k) * G3 + j];
        float2 s = *(const float2*)&sm[k * 36 + bg * 2];
        fma4(a0, w, s.x);
        fma4(a1, w, s.y);
    }
    int b = bg * 2;
    *(float4*)&ob[((size_t)ks * BB + b) * G3 + j] = a0;
    *(float4*)&ob[((size_t)ks * BB + b + 1) * G3 + j] = a1;
}

// ---------------- K2: per-b everything-else. 32 blocks x 1024 threads ----------------
// combine -> h(t); q = h@W2; scores+softmax over L; ctx; out_state -> los slot t+1.
__global__ void __launch_bounds__(1024) k_step(
    const float* __restrict__ mxp, const float* __restrict__ mhp,
    const float* __restrict__ gruB, const float* __restrict__ W2,
    const float* __restrict__ V, const float* __restrict__ fp,
    const float* __restrict__ features, const float* __restrict__ outW,
    float* __restrict__ h, float* __restrict__ los, int t) {
    __shared__ float sh[RNND];   // h(t)
    __shared__ float sc[FEATD];  // ctx (normalized)
    __shared__ float sq[ATTD];   // q
    __shared__ float sV[ATTD];
    __shared__ float sw[LL];     // exp(score)
    __shared__ float sred[1024];
    __shared__ float sinv[1];
    int b = blockIdx.x, tid = threadIdx.x;

    // Phase A: GRU combine (threads 0..511), V staging (512..1023)
    if (tid < 512) {
        int j = tid;
        size_t m0 = (size_t)(0 * BB + b) * G3, m1 = (size_t)(1 * BB + b) * G3,
               m2 = (size_t)(2 * BB + b) * G3;
        float xz = gruB[j] + mxp[m0 + j] + mxp[m1 + j] + mxp[m2 + j];
        float xr = gruB[512 + j] + mxp[m0 + 512 + j] + mxp[m1 + 512 + j] + mxp[m2 + 512 + j];
        float xh = gruB[1024 + j] + mxp[m0 + 1024 + j] + mxp[m1 + 1024 + j] + mxp[m2 + 1024 + j];
        float rz = gruB[G3 + j] + mhp[m0 + j] + mhp[m1 + j];
        float rr = gruB[G3 + 512 + j] + mhp[m0 + 512 + j] + mhp[m1 + 512 + j];
        float rh = gruB[G3 + 1024 + j] + mhp[m0 + 1024 + j] + mhp[m1 + 1024 + j];
        float z = fsigmoid(xz + rz), r = fsigmoid(xr + rr);
        float hh = ftanh(xh + r * rh);
        float hn = z * h[(size_t)b * RNND + j] + (1.f - z) * hh;
        h[(size_t)b * RNND + j] = hn;
        sh[j] = hn;
    } else {
        sV[tid - 512] = V[tid - 512];
    }
    __syncthreads();

    // Phase B: q = h @ W2, split-k halves
    {
        int a = tid & 511, half = tid >> 9;
        int kb = half * 256;
        float acc = 0.f;
#pragma unroll 8
        for (int k = 0; k < 256; ++k) acc += sh[kb + k] * W2[(size_t)(kb + k) * ATTD + a];
        sred[tid] = acc;
    }
    __syncthreads();
    if (tid < 512) sq[tid] = sred[tid] + sred[512 + tid];
    __syncthreads();

    // Phase C: scores -> exp. 16 waves, each handles l = wv, wv+16, ...
    {
        int lane = tid & 63, wv = tid >> 6;
        float4 q0 = ((const float4*)sq)[lane], q1 = ((const float4*)sq)[64 + lane];
        float4 v0 = ((const float4*)sV)[lane], v1 = ((const float4*)sV)[64 + lane];
        for (int l = wv; l < LL; l += 16) {
            const float4* row = (const float4*)(fp + ((size_t)b * LL + l) * ATTD);
            float4 f0 = row[lane], f1 = row[64 + lane];
            float d = ftanh(f0.x + q0.x) * v0.x + ftanh(f0.y + q0.y) * v0.y +
                      ftanh(f0.z + q0.z) * v0.z + ftanh(f0.w + q0.w) * v0.w +
                      ftanh(f1.x + q1.x) * v1.x + ftanh(f1.y + q1.y) * v1.y +
                      ftanh(f1.z + q1.z) * v1.z + ftanh(f1.w + q1.w) * v1.w;
#pragma unroll
            for (int o = 32; o > 0; o >>= 1) d += __shfl_xor(d, o);
            if (lane == 0) sw[l] = __expf(d);  // |score| <= sum|V| ~ 20, fp32-safe
        }
    }
    __syncthreads();

    // Phase D: denominator
    if (tid < 512) sred[tid] = (tid < LL) ? sw[tid] : 0.f;
    __syncthreads();
#pragma unroll
    for (int s = 256; s > 0; s >>= 1) {
        if (tid < s) sred[tid] += sred[tid + s];
        __syncthreads();
    }
    if (tid == 0) sinv[0] = 1.f / sred[0];
    __syncthreads();

    // Phase E: ctx[f] = (sum_l w[l]*features[b,l,f]) * inv, split-l halves
    {
        int f = tid & 511, half = tid >> 9;
        int l0 = half * 200;
        float acc = 0.f;
#pragma unroll 4
        for (int l = 0; l < 200; ++l)
            acc += sw[l0 + l] * features[((size_t)b * LL + l0 + l) * FEATD + f];
        sred[tid] = acc;
    }
    __syncthreads();
    if (tid < 512) sc[tid] = (sred[tid] + sred[512 + tid]) * sinv[0];
    __syncthreads();

    // Phase F: out_state = tanh(cat(h,ctx) @ outW), split-k halves -> los slot t+1
    {
        int j = tid & 511, half = tid >> 9;
        const float* src = half ? sc : sh;
        const float* Wb = outW + (size_t)half * 512 * RNND;
        float acc = 0.f;
#pragma unroll 8
        for (int k = 0; k < 512; ++k) acc += src[k] * Wb[(size_t)k * RNND + j];
        sred[tid] = acc;
    }
    __syncthreads();
    if (tid < 512)
        los[((size_t)(t + 1) * BB + b) * RNND + tid] = ftanh(sred[tid] + sred[512 + tid]);
}

// ---------------- final: logits = los[1..150] @ projW, one big GEMM ----------------
// rows r = b*150+t (matches out[B][T][V] row-major). 75 row-tiles x 40 v-tiles.
__global__ void __launch_bounds__(256) k_final(
    const float* __restrict__ los, const float* __restrict__ Wp,
    float* __restrict__ out) {
    __shared__ float sa[64 * 68];
    __shared__ unsigned srow[64];
    int mt = blockIdx.x / 40, vt = blockIdx.x % 40;
    int r0 = mt * 64;
    int tid = threadIdx.x;
    if (tid < 64) {
        int r = r0 + tid;
        int bb = r / TT, t = r % TT;
        srow[tid] = (unsigned)(((size_t)(t + 1) * BB + bb) * RNND);
    }
    int aq = tid & 31, blg = tid >> 5;
    int v = vt * 128 + aq * 4;
    bool vok = v < VOCABD;
    float4 acc[8] = {};
    __syncthreads();
    for (int kc = 0; kc < RNND; kc += 64) {
        for (int it = 0; it < 16; ++it) {
            int lin = it * 256 + tid;
            int k = lin & 63, rl = lin >> 6;
            sa[k * 68 + rl] = los[srow[rl] + kc + k];
        }
        __syncthreads();
        if (vok) {
#pragma unroll 4
            for (int k = 0; k < 64; ++k) {
                float4 w = *(const float4*)&Wp[(size_t)(kc + k) * VOCABD + v];
                float4 s0 = *(const float4*)&sa[k * 68 + blg * 8];
                float4 s1 = *(const float4*)&sa[k * 68 + blg * 8 + 4];
                fma4(acc[0], w, s0.x); fma4(acc[1], w, s0.y);
                fma4(acc[2], w, s0.z); fma4(acc[3], w, s0.w);
                fma4(acc[4], w, s1.x); fma4(acc[5], w, s1.y);
                fma4(acc[6], w, s1.z); fma4(acc[7], w, s1.w);
            }
        }
        __syncthreads();
    }
    if (vok) {
#pragma unroll
        for (int i = 0; i < 8; ++i)
            *(float4*)&out[(size_t)(r0 + blg * 8 + i) * VOCABD + v] = acc[i];
    }
}

extern "C" void kernel_launch(void* const* d_in, const int* in_sizes, int n_in,
                              void* d_out, int out_size, void* d_ws, size_t ws_size,
                              hipStream_t stream) {
    const float* features  = (const float*)d_in[0];
    const float* initstate = (const float*)d_in[1];
    const float* emb       = (const float*)d_in[2];
    const float* gruK      = (const float*)d_in[3];
    const float* gruR      = (const float*)d_in[4];
    const float* gruB      = (const float*)d_in[5];
    const float* W1        = (const float*)d_in[6];
    const float* W2        = (const float*)d_in[7];
    const float* V         = (const float*)d_in[8];
    const float* outW      = (const float*)d_in[9];
    const float* projW     = (const float*)d_in[10];
    const int*   formula   = (const int*)d_in[11];
    float* logits = (float*)d_out;

    float* ws = (float*)d_ws;
    float* h    = ws;                                   // 16,384
    float* mxp  = h + (size_t)BB * RNND;                // 3*32*1536
    float* mhp  = mxp + (size_t)3 * BB * G3;            // 2*32*1536
    float* los  = mhp + (size_t)2 * BB * G3;            // 151*32*512
    float* fp   = los + (size_t)(TT + 1) * BB * RNND;   // 32*400*512

    // los slot 0 = lo before step 0 = zeros (re-zeroed every call: deterministic)
    hipMemsetAsync(los, 0, (size_t)BB * RNND * sizeof(float), stream);
    hipMemcpyAsync(h, initstate, (size_t)BB * RNND * sizeof(float),
                   hipMemcpyDeviceToDevice, stream);

    k_feat_proj<<<800, 256, 0, stream>>>(features, W1, fp);

    for (int t = 0; t < TT; ++t) {
        k_gates<<<120, 256, 0, stream>>>(emb, formula, gruK, gruR, h, los, mxp, mhp, t);
        k_step<<<BB, 1024, 0, stream>>>(mxp, mhp, gruB, W2, V, fp, features, outW,
                                        h, los, t);
    }
    k_final<<<75 * 40, 256, 0, stream>>>(los, projW, logits);
}

// Round 6
// 15324.574 us; speedup vs baseline: 4.5812x; 1.2400x over previous
//
#include <hip/hip_runtime.h>

#define BB 32
#define TT 150
#define LL 400
#define FEATD 512
#define RNND 512
#define ATTD 512
#define EMBD 256
#define VOCABD 5000
#define G3 1536

__device__ __forceinline__ float fsigmoid(float x) { return 1.f / (1.f + __expf(-x)); }
__device__ __forceinline__ float ftanh(float x) {
    x = fminf(15.f, fmaxf(-15.f, x));
    float e = __expf(2.f * x);
    return 1.f - 2.f / (e + 1.f);
}
__device__ __forceinline__ void fma4(float4& a, const float4 w, const float s) {
    a.x += w.x * s; a.y += w.y * s; a.z += w.z * s; a.w += w.w * s;
}

// ---------------- one-time feat_proj: [B*L,512] @ [512,512] -> fp ----------------
__global__ void __launch_bounds__(256) k_feat_proj(const float* __restrict__ features,
                                                   const float* __restrict__ W1,
                                                   float* __restrict__ fp) {
    __shared__ float sa[64 * 68];
    int blt = blockIdx.x >> 2, at = blockIdx.x & 3;
    int bl0 = blt * 64;
    int tid = threadIdx.x;
    int aq = tid & 31, blg = tid >> 5;
    float4 acc[8] = {};
    for (int kc = 0; kc < FEATD; kc += 64) {
        __syncthreads();
        for (int it = 0; it < 16; ++it) {
            int lin = it * 256 + tid;
            int k = lin & 63, bl = lin >> 6;
            sa[k * 68 + bl] = features[((size_t)bl0 + bl) * FEATD + kc + k];
        }
        __syncthreads();
#pragma unroll 4
        for (int k = 0; k < 64; ++k) {
            float4 w = *(const float4*)&W1[(size_t)(kc + k) * ATTD + at * 128 + aq * 4];
            float4 s0 = *(const float4*)&sa[k * 68 + blg * 8];
            float4 s1 = *(const float4*)&sa[k * 68 + blg * 8 + 4];
            fma4(acc[0], w, s0.x); fma4(acc[1], w, s0.y);
            fma4(acc[2], w, s0.z); fma4(acc[3], w, s0.w);
            fma4(acc[4], w, s1.x); fma4(acc[5], w, s1.y);
            fma4(acc[6], w, s1.z); fma4(acc[7], w, s1.w);
        }
    }
#pragma unroll
    for (int i = 0; i < 8; ++i)
        *(float4*)&fp[((size_t)bl0 + blg * 8 + i) * ATTD + at * 128 + aq * 4] = acc[i];
}

// ---------------- K1: gate GEMM partials. 120 blocks ----------------
// mx: [emb(tok) | tanh(sum outpp)] (K=768) @ Wk -> mxp[3], mh: h(t-1) @ Wr -> mhp[2].
// Side effect: jt==0 mx-ks1/2 blocks write lo(t-1) to los slot t-1 (for k_final).
__global__ void __launch_bounds__(256) k_gates(
    const float* __restrict__ emb, const int* __restrict__ formula,
    const float* __restrict__ Wk, const float* __restrict__ Wr,
    const float* __restrict__ hin, const float* __restrict__ outpp,
    float* __restrict__ mxp, float* __restrict__ mhp,
    float* __restrict__ los, int t) {
    __shared__ float sm[256 * 36];
    __shared__ int stok[BB];
    int id = blockIdx.x, tid = threadIdx.x;
    bool isMX = id < 72;
    int jt, ks; const float* W; float* ob;
    if (isMX) { jt = id / 3; ks = id % 3; W = Wk; ob = mxp; }
    else { int r = id - 72; jt = r >> 1; ks = r & 1; W = Wr; ob = mhp; }
    int k0 = ks * 256;
    if (isMX && ks == 0 && tid < BB) stok[tid] = formula[tid * TT + t];
    __syncthreads();
    // stage activations sm[k*36+b]
    for (int it = 0; it < 32; ++it) {
        int lin = it * 256 + tid;
        int k = lin & 255, b = lin >> 8;
        float v;
        if (!isMX) {
            v = hin[(size_t)b * RNND + k0 + k];
        } else if (ks == 0) {
            v = emb[(size_t)stok[b] * EMBD + k];
        } else {
            int kr = (ks - 1) * 256 + k;  // last_out = tanh(sum of 4 out partials)
            v = ftanh(outpp[(size_t)(0 * BB + b) * RNND + kr] +
                      outpp[(size_t)(1 * BB + b) * RNND + kr] +
                      outpp[(size_t)(2 * BB + b) * RNND + kr] +
                      outpp[(size_t)(3 * BB + b) * RNND + kr]);
            if (jt == 0 && t > 0)
                los[((size_t)(t - 1) * BB + b) * RNND + kr] = v;
        }
        sm[k * 36 + b] = v;
    }
    __syncthreads();
    int jq = tid & 15, bg = tid >> 4;
    int j = jt * 64 + jq * 4;
    float4 a0 = {0, 0, 0, 0}, a1 = {0, 0, 0, 0};
#pragma unroll 4
    for (int k = 0; k < 256; ++k) {
        float4 w = *(const float4*)&W[(size_t)(k0 + k) * G3 + j];
        float2 s = *(const float2*)&sm[k * 36 + bg * 2];
        fma4(a0, w, s.x);
        fma4(a1, w, s.y);
    }
    int b = bg * 2;
    *(float4*)&ob[((size_t)ks * BB + b) * G3 + j] = a0;
    *(float4*)&ob[((size_t)ks * BB + b + 1) * G3 + j] = a1;
}

// ---------------- K2: GRU combine -> h(t) (ping-pong) + q slice. 256 blocks ----------------
// block = b(32) x as(8). Every block recomputes h(b) (cheap, ~30KB reads);
// only as==0 writes hout. q[b, as*64..+64] via 4-way split-k + LDS reduce.
__global__ void __launch_bounds__(256) k_combine_q(
    const float* __restrict__ mxp, const float* __restrict__ mhp,
    const float* __restrict__ gruB, const float* __restrict__ W2,
    const float* __restrict__ hin, float* __restrict__ hout,
    float* __restrict__ q) {
    __shared__ float sh[RNND];
    __shared__ float sred[256];
    int b = blockIdx.x >> 3, as = blockIdx.x & 7;
    int tid = threadIdx.x;
    size_t m0 = (size_t)(0 * BB + b) * G3, m1 = (size_t)(1 * BB + b) * G3,
           m2 = (size_t)(2 * BB + b) * G3;
#pragma unroll
    for (int jj = 0; jj < 2; ++jj) {
        int j = tid + jj * 256;
        float xz = gruB[j] + mxp[m0 + j] + mxp[m1 + j] + mxp[m2 + j];
        float xr = gruB[512 + j] + mxp[m0 + 512 + j] + mxp[m1 + 512 + j] + mxp[m2 + 512 + j];
        float xh = gruB[1024 + j] + mxp[m0 + 1024 + j] + mxp[m1 + 1024 + j] + mxp[m2 + 1024 + j];
        float rz = gruB[G3 + j] + mhp[m0 + j] + mhp[m1 + j];
        float rr = gruB[G3 + 512 + j] + mhp[m0 + 512 + j] + mhp[m1 + 512 + j];
        float rh = gruB[G3 + 1024 + j] + mhp[m0 + 1024 + j] + mhp[m1 + 1024 + j];
        float z = fsigmoid(xz + rz), r = fsigmoid(xr + rr);
        float hh = ftanh(xh + r * rh);
        float hn = z * hin[(size_t)b * RNND + j] + (1.f - z) * hh;
        sh[j] = hn;
        if (as == 0) hout[(size_t)b * RNND + j] = hn;
    }
    __syncthreads();
    int a = as * 64 + (tid & 63), kq = tid >> 6;
    float acc = 0.f;
    int kb = kq * 128;
#pragma unroll 8
    for (int k = 0; k < 128; ++k) acc += sh[kb + k] * W2[(size_t)(kb + k) * ATTD + a];
    sred[tid] = acc;
    __syncthreads();
    if (tid < 64)
        q[(size_t)b * ATTD + as * 64 + tid] =
            sred[tid] + sred[tid + 64] + sred[tid + 128] + sred[tid + 192];
}

// ---------------- K3: scores + exp + ctx partials. 256 blocks = b(32) x ls(8) ----------------
__global__ void __launch_bounds__(256) k_attn(
    const float* __restrict__ q, const float* __restrict__ fp,
    const float* __restrict__ V, const float* __restrict__ features,
    float* __restrict__ ctxp, float* __restrict__ esump) {
    __shared__ float sq[ATTD];
    __shared__ float sV[ATTD];
    __shared__ float se[64];
    int b = blockIdx.x >> 3, ls = blockIdx.x & 7, l0 = ls * 50;
    int tid = threadIdx.x;
    sq[tid] = q[(size_t)b * ATTD + tid];
    sq[tid + 256] = q[(size_t)b * ATTD + tid + 256];
    sV[tid] = V[tid];
    sV[tid + 256] = V[tid + 256];
    if (tid >= 50 && tid < 64) se[tid] = 0.f;
    __syncthreads();
    int lane = tid & 63, wv = tid >> 6;
    float4 q0 = ((const float4*)sq)[lane], q1 = ((const float4*)sq)[64 + lane];
    float4 v0 = ((const float4*)sV)[lane], v1 = ((const float4*)sV)[64 + lane];
    for (int ll = wv; ll < 50; ll += 4) {
        const float4* row = (const float4*)(fp + ((size_t)b * LL + l0 + ll) * ATTD);
        float4 f0 = row[lane], f1 = row[64 + lane];
        float d = ftanh(f0.x + q0.x) * v0.x + ftanh(f0.y + q0.y) * v0.y +
                  ftanh(f0.z + q0.z) * v0.z + ftanh(f0.w + q0.w) * v0.w +
                  ftanh(f1.x + q1.x) * v1.x + ftanh(f1.y + q1.y) * v1.y +
                  ftanh(f1.z + q1.z) * v1.z + ftanh(f1.w + q1.w) * v1.w;
#pragma unroll
        for (int o = 32; o > 0; o >>= 1) d += __shfl_xor(d, o);
        if (lane == 0) se[ll] = __expf(d);  // |score| <= sum|V| ~ 20, fp32-safe
    }
    __syncthreads();
    if (tid < 64) {
        float x = se[tid];
#pragma unroll
        for (int o = 32; o > 0; o >>= 1) x += __shfl_xor(x, o);
        if (tid == 0) esump[ls * BB + b] = x;
    }
    float c0 = 0.f, c1 = 0.f;
#pragma unroll 2
    for (int l = 0; l < 50; ++l) {
        float e = se[l];
        const float* fr = features + ((size_t)b * LL + l0 + l) * FEATD;
        c0 += e * fr[tid];
        c1 += e * fr[tid + 256];
    }
    ctxp[((size_t)ls * BB + b) * FEATD + tid] = c0;
    ctxp[((size_t)ls * BB + b) * FEATD + tid + 256] = c1;
}

// ---------------- K4: out_state pre-act partials. 32 blocks = jt(8) x ks(4) ----------------
__global__ void __launch_bounds__(256) k_outstate(
    const float* __restrict__ h, const float* __restrict__ ctxp,
    const float* __restrict__ esump, const float* __restrict__ outW,
    float* __restrict__ outpp) {
    __shared__ float sm[256 * 36];
    __shared__ float sinv[BB];
    int jt = blockIdx.x >> 2, ks = blockIdx.x & 3;
    int tid = threadIdx.x;
    if (tid < BB) {
        float s = 0.f;
#pragma unroll
        for (int ls = 0; ls < 8; ++ls) s += esump[ls * BB + tid];
        sinv[tid] = 1.f / s;
    }
    __syncthreads();
    int k0 = ks * 256;
    for (int it = 0; it < 32; ++it) {
        int lin = it * 256 + tid;
        int k = lin & 255, b = lin >> 8;
        int kk = k0 + k;
        float v;
        if (kk < RNND) {
            v = h[(size_t)b * RNND + kk];
        } else {
            int f = kk - RNND;
            float c = 0.f;
#pragma unroll
            for (int ls = 0; ls < 8; ++ls) c += ctxp[((size_t)ls * BB + b) * FEATD + f];
            v = c * sinv[b];
        }
        sm[k * 36 + b] = v;
    }
    __syncthreads();
    int jq = tid & 15, bg = tid >> 4;
    int j = jt * 64 + jq * 4;
    float4 a0 = {0, 0, 0, 0}, a1 = {0, 0, 0, 0};
#pragma unroll 4
    for (int k = 0; k < 256; ++k) {
        float4 w = *(const float4*)&outW[(size_t)(k0 + k) * RNND + j];
        float2 s = *(const float2*)&sm[k * 36 + bg * 2];
        fma4(a0, w, s.x);
        fma4(a1, w, s.y);
    }
    int b = bg * 2;
    *(float4*)&outpp[((size_t)ks * BB + b) * RNND + j] = a0;
    *(float4*)&outpp[((size_t)ks * BB + b + 1) * RNND + j] = a1;
}

// ---------------- tail: materialize lo(149) into los slot 149 ----------------
__global__ void __launch_bounds__(256) k_lo_tail(const float* __restrict__ outpp,
                                                 float* __restrict__ los) {
    int b = blockIdx.x, tid = threadIdx.x;
#pragma unroll
    for (int jj = 0; jj < 2; ++jj) {
        int j = tid + jj * 256;
        float s = outpp[(size_t)(0 * BB + b) * RNND + j] +
                  outpp[(size_t)(1 * BB + b) * RNND + j] +
                  outpp[(size_t)(2 * BB + b) * RNND + j] +
                  outpp[(size_t)(3 * BB + b) * RNND + j];
        los[((size_t)(TT - 1) * BB + b) * RNND + j] = ftanh(s);
    }
}

// ---------------- final: logits = los @ projW, one big GEMM ----------------
// row r = b*150+t  ->  los slot (t*BB+b). 75 row-tiles x 40 v-tiles.
__global__ void __launch_bounds__(256) k_final(
    const float* __restrict__ los, const float* __restrict__ Wp,
    float* __restrict__ out) {
    __shared__ float sa[64 * 68];
    __shared__ unsigned srow[64];
    int mt = blockIdx.x / 40, vt = blockIdx.x % 40;
    int r0 = mt * 64;
    int tid = threadIdx.x;
    if (tid < 64) {
        int r = r0 + tid;
        int bb = r / TT, t = r % TT;
        srow[tid] = (unsigned)(((size_t)t * BB + bb) * RNND);
    }
    int aq = tid & 31, blg = tid >> 5;
    int v = vt * 128 + aq * 4;
    bool vok = v < VOCABD;
    float4 acc[8] = {};
    __syncthreads();
    for (int kc = 0; kc < RNND; kc += 64) {
        for (int it = 0; it < 16; ++it) {
            int lin = it * 256 + tid;
            int k = lin & 63, rl = lin >> 6;
            sa[k * 68 + rl] = los[srow[rl] + kc + k];
        }
        __syncthreads();
        if (vok) {
#pragma unroll 4
            for (int k = 0; k < 64; ++k) {
                float4 w = *(const float4*)&Wp[(size_t)(kc + k) * VOCABD + v];
                float4 s0 = *(const float4*)&sa[k * 68 + blg * 8];
                float4 s1 = *(const float4*)&sa[k * 68 + blg * 8 + 4];
                fma4(acc[0], w, s0.x); fma4(acc[1], w, s0.y);
                fma4(acc[2], w, s0.z); fma4(acc[3], w, s0.w);
                fma4(acc[4], w, s1.x); fma4(acc[5], w, s1.y);
                fma4(acc[6], w, s1.z); fma4(acc[7], w, s1.w);
            }
        }
        __syncthreads();
    }
    if (vok) {
#pragma unroll
        for (int i = 0; i < 8; ++i)
            *(float4*)&out[(size_t)(r0 + blg * 8 + i) * VOCABD + v] = acc[i];
    }
}

extern "C" void kernel_launch(void* const* d_in, const int* in_sizes, int n_in,
                              void* d_out, int out_size, void* d_ws, size_t ws_size,
                              hipStream_t stream) {
    const float* features  = (const float*)d_in[0];
    const float* initstate = (const float*)d_in[1];
    const float* emb       = (const float*)d_in[2];
    const float* gruK      = (const float*)d_in[3];
    const float* gruR      = (const float*)d_in[4];
    const float* gruB      = (const float*)d_in[5];
    const float* W1        = (const float*)d_in[6];
    const float* W2        = (const float*)d_in[7];
    const float* V         = (const float*)d_in[8];
    const float* outW      = (const float*)d_in[9];
    const float* projW     = (const float*)d_in[10];
    const int*   formula   = (const int*)d_in[11];
    float* logits = (float*)d_out;

    float* ws = (float*)d_ws;
    float* h0    = ws;                                  // 16,384
    float* h1    = h0 + (size_t)BB * RNND;              // 16,384
    float* mxp   = h1 + (size_t)BB * RNND;              // 147,456
    float* mhp   = mxp + (size_t)3 * BB * G3;           // 98,304
    float* q     = mhp + (size_t)2 * BB * G3;           // 16,384
    float* ctxp  = q + (size_t)BB * ATTD;               // 131,072
    float* esump = ctxp + (size_t)8 * BB * FEATD;       // 256
    float* outpp = esump + 8 * BB;                      // 65,536
    float* los   = outpp + (size_t)4 * BB * RNND;       // 2,457,600
    float* fp    = los + (size_t)TT * BB * RNND;        // 6,553,600

    // outpp zero => lo(t=0)=tanh(0)=0; re-zeroed every call (deterministic).
    hipMemsetAsync(outpp, 0, (size_t)4 * BB * RNND * sizeof(float), stream);
    hipMemcpyAsync(h0, initstate, (size_t)BB * RNND * sizeof(float),
                   hipMemcpyDeviceToDevice, stream);

    k_feat_proj<<<800, 256, 0, stream>>>(features, W1, fp);

    float* hin = h0;
    float* hout = h1;
    for (int t = 0; t < TT; ++t) {
        k_gates<<<120, 256, 0, stream>>>(emb, formula, gruK, gruR, hin, outpp,
                                         mxp, mhp, los, t);
        k_combine_q<<<256, 256, 0, stream>>>(mxp, mhp, gruB, W2, hin, hout, q);
        k_attn<<<256, 256, 0, stream>>>(q, fp, V, features, ctxp, esump);
        k_outstate<<<32, 256, 0, stream>>>(hout, ctxp, esump, outW, outpp);
        float* tmp = hin; hin = hout; hout = tmp;
    }
    k_lo_tail<<<BB, 256, 0, stream>>>(outpp, los);
    k_final<<<75 * 40, 256, 0, stream>>>(los, projW, logits);
}